// Round 1
// baseline (51.806 us; speedup 1.0000x reference)
//
#include <hip/hip_runtime.h>
#include <math.h>

#define BB 16
#define TT 60
#define NN 196
#define CC 512
#define HH 4
#define DD 128
#define TOPM 10

// ---------------------------------------------------------------------------
// Kernel A: q[e] = sum_c qst[0,c] * Wq[e,c] + bq[e]   (e = 0..511)
// one wave (64 lanes) per output e; coalesced float4 reads of Wq row.
// ---------------------------------------------------------------------------
__global__ void k_q(const float* __restrict__ qst, const float* __restrict__ Wq,
                    const float* __restrict__ bq, float* __restrict__ q) {
    int wave = (blockIdx.x * blockDim.x + threadIdx.x) >> 6;   // 0..511 == e
    int lane = threadIdx.x & 63;
    const float4* row = (const float4*)(Wq + (size_t)wave * CC);
    const float4* qs  = (const float4*)qst;                    // b=0 row
    float acc = 0.f;
#pragma unroll
    for (int j = 0; j < 2; ++j) {
        int c4 = lane * 2 + j;                                 // 128 float4 per row
        float4 w = row[c4];
        float4 xv = qs[c4];
        acc += w.x * xv.x + w.y * xv.y + w.z * xv.z + w.w * xv.w;
    }
#pragma unroll
    for (int off = 32; off; off >>= 1) acc += __shfl_xor(acc, off);
    if (lane == 0) q[wave] = acc + bq[wave];
}

// ---------------------------------------------------------------------------
// Kernel B: qW[h,c] = sum_d q[h*128+d] * Wk[(h*128+d), c]
//           qb[h]   = sum_d q[h*128+d] * bk[h*128+d]
// thread t -> (h = t>>9, c = t&511). q loads are wave-uniform (scalar);
// Wk reads are coalesced across c.
// ---------------------------------------------------------------------------
__global__ void k_qw(const float* __restrict__ q, const float* __restrict__ Wk,
                     const float* __restrict__ bk, float* __restrict__ qW,
                     float* __restrict__ qb) {
    int t = blockIdx.x * blockDim.x + threadIdx.x;             // 0..2047
    int c = t & (CC - 1);
    int h = t >> 9;
    float acc = 0.f;
    for (int d = 0; d < DD; ++d)
        acc += q[h * DD + d] * Wk[(size_t)(h * DD + d) * CC + c];
    qW[h * CC + c] = acc;
    if (t < HH) {
        float s = 0.f;
        for (int d = 0; d < DD; ++d) s += q[t * DD + d] * bk[t * DD + d];
        qb[t] = s;
    }
}

// ---------------------------------------------------------------------------
// Kernel C (single block, 1024 threads):
//   scores[h,n] = scale * (dot(x[0,0,n,:], qW[h,:]) + qb[h])
//   softmax over n per h, patch_weights[n] = mean_h attn[h,n]
//   p = max index among top-10 patch_weights  -> *pOut
// ---------------------------------------------------------------------------
__global__ void __launch_bounds__(1024) k_select(
        const float* __restrict__ x, const float* __restrict__ qWg,
        const float* __restrict__ qbg, int* __restrict__ pOut) {
    __shared__ float qW[HH * CC];
    __shared__ float qb[HH];
    __shared__ float sc[HH][NN];
    __shared__ float mh[HH], dh[HH];
    __shared__ float pw[NN];

    int tid = threadIdx.x;
    for (int i = tid; i < HH * CC; i += 1024) qW[i] = qWg[i];
    if (tid < HH) qb[tid] = qbg[tid];
    __syncthreads();

    int wv = tid >> 6, lane = tid & 63;
    const float scale = 0.08838834764831845f;                  // 1/sqrt(128)

    // scores: each wave owns n = wv, wv+16, ... ; computes all 4 heads per row
    for (int n = wv; n < NN; n += 16) {
        const float4* xr = (const float4*)(x + (size_t)n * CC); // x[0,0,n,:]
        int c4a = lane * 2, c4b = c4a + 1;
        float4 xa = xr[c4a], xb = xr[c4b];
#pragma unroll
        for (int h = 0; h < HH; ++h) {
            const float* qwr = qW + h * CC;
            float acc = xa.x * qwr[c4a * 4 + 0] + xa.y * qwr[c4a * 4 + 1] +
                        xa.z * qwr[c4a * 4 + 2] + xa.w * qwr[c4a * 4 + 3] +
                        xb.x * qwr[c4b * 4 + 0] + xb.y * qwr[c4b * 4 + 1] +
                        xb.z * qwr[c4b * 4 + 2] + xb.w * qwr[c4b * 4 + 3];
#pragma unroll
            for (int off = 32; off; off >>= 1) acc += __shfl_xor(acc, off);
            if (lane == 0) sc[h][n] = scale * (acc + qb[h]);
        }
    }
    __syncthreads();

    // per-head softmax stats (waves 0..3)
    if (wv < HH) {
        int h = wv;
        float m = -1e30f;
        for (int n = lane; n < NN; n += 64) m = fmaxf(m, sc[h][n]);
#pragma unroll
        for (int off = 32; off; off >>= 1) m = fmaxf(m, __shfl_xor(m, off));
        float s = 0.f;
        for (int n = lane; n < NN; n += 64) s += expf(sc[h][n] - m);
#pragma unroll
        for (int off = 32; off; off >>= 1) s += __shfl_xor(s, off);
        if (lane == 0) { mh[h] = m; dh[h] = s; }
    }
    __syncthreads();

    // patch_weights
    if (tid < NN) {
        float v = 0.f;
#pragma unroll
        for (int h = 0; h < HH; ++h) v += expf(sc[h][tid] - mh[h]) / dh[h];
        pw[tid] = 0.25f * v;
    }
    __syncthreads();

    // top-10 selection on wave 0, values held in registers (no LDS masking races)
    if (wv == 0) {
        float v0 = (lane + 0   < NN) ? pw[lane + 0]   : -2e30f;
        float v1 = (lane + 64  < NN) ? pw[lane + 64]  : -2e30f;
        float v2 = (lane + 128 < NN) ? pw[lane + 128] : -2e30f;
        float v3 = (lane + 192 < NN) ? pw[lane + 192] : -2e30f;
        int p = -1;
        for (int r = 0; r < TOPM; ++r) {
            float v = -3e30f; int idx = -1;
            // per-lane max (ascending j, >= prefers larger index on ties)
            if (v0 >= v) { v = v0; idx = lane + 0; }
            if (v1 >= v) { v = v1; idx = lane + 64; }
            if (v2 >= v) { v = v2; idx = lane + 128; }
            if (v3 >= v) { v = v3; idx = lane + 192; }
#pragma unroll
            for (int off = 32; off; off >>= 1) {
                float vo = __shfl_xor(v, off);
                int   io = __shfl_xor(idx, off);
                if (vo > v || (vo == v && io > idx)) { v = vo; idx = io; }
            }
            // winner masks its register copy
            if ((idx & 63) == lane) {
                int jj = idx >> 6;
                if (jj == 0) v0 = -2e30f;
                else if (jj == 1) v1 = -2e30f;
                else if (jj == 2) v2 = -2e30f;
                else v3 = -2e30f;
            }
            if (idx > p) p = idx;
        }
        if (lane == 0) *pOut = p;
    }
}

// ---------------------------------------------------------------------------
// Kernel D: out0[b,t,m,c] = x[b,t,p,c]; out1 = identical copy right after.
// thread t -> (bt = t>>7, c4 = t&127); each thread 1 float4 load, 20 stores.
// ---------------------------------------------------------------------------
__global__ void k_bcast(const float* __restrict__ x, const int* __restrict__ pPtr,
                        float* __restrict__ out) {
    int t = blockIdx.x * blockDim.x + threadIdx.x;             // 0..BB*TT*128-1
    int p  = *pPtr;
    int bt = t >> 7;
    int c4 = t & 127;
    float4 v = ((const float4*)x)[((size_t)bt * NN + p) * 128 + c4];
    float4* o0 = (float4*)out + ((size_t)bt * TOPM) * 128 + c4;
    float4* o1 = o0 + (size_t)BB * TT * TOPM * 128;
#pragma unroll
    for (int m = 0; m < TOPM; ++m) {
        o0[(size_t)m * 128] = v;
        o1[(size_t)m * 128] = v;
    }
}

extern "C" void kernel_launch(void* const* d_in, const int* in_sizes, int n_in,
                              void* d_out, int out_size, void* d_ws, size_t ws_size,
                              hipStream_t stream) {
    const float* x   = (const float*)d_in[0];   // (16,60,196,512)
    const float* qst = (const float*)d_in[1];   // (16,512)
    const float* Wq  = (const float*)d_in[2];   // (512,512)
    const float* bq  = (const float*)d_in[3];   // (512,)
    const float* Wk  = (const float*)d_in[4];   // (512,512)
    const float* bk  = (const float*)d_in[5];   // (512,)

    float* ws  = (float*)d_ws;
    float* q   = ws;            // 512
    float* qW  = ws + 512;      // 2048
    float* qb  = ws + 2560;     // 4
    int*   p   = (int*)(ws + 2564);

    k_q     <<<128, 256, 0, stream>>>(qst, Wq, bq, q);
    k_qw    <<<8,   256, 0, stream>>>(q, Wk, bk, qW, qb);
    k_select<<<1,  1024, 0, stream>>>(x, qW, qb, p);
    k_bcast <<<(BB * TT * 128) / 256, 256, 0, stream>>>(x, p, (float*)d_out);
}

// Round 2
// 31.679 us; speedup vs baseline: 1.6354x; 1.6354x over previous
//
#include <hip/hip_runtime.h>
#include <math.h>

#define BB 16
#define TT 60
#define NN 196
#define CC 512
#define HH 4
#define DD 128
#define TOPM 10

// ---------------------------------------------------------------------------
// Kernel A: q[e] = sum_c qst[0,c] * Wq[e,c] + bq[e]   (e = 0..511)
// one wave per output e; coalesced float4 reads of Wq row.
// ---------------------------------------------------------------------------
__global__ void k_q(const float* __restrict__ qst, const float* __restrict__ Wq,
                    const float* __restrict__ bq, float* __restrict__ q) {
    int wave = (blockIdx.x * blockDim.x + threadIdx.x) >> 6;   // 0..511 == e
    int lane = threadIdx.x & 63;
    const float4* row = (const float4*)(Wq + (size_t)wave * CC);
    const float4* qs  = (const float4*)qst;                    // b=0 row
    float acc = 0.f;
#pragma unroll
    for (int j = 0; j < 2; ++j) {
        int c4 = lane * 2 + j;
        float4 w = row[c4];
        float4 xv = qs[c4];
        acc += w.x * xv.x + w.y * xv.y + w.z * xv.z + w.w * xv.w;
    }
#pragma unroll
    for (int off = 32; off; off >>= 1) acc += __shfl_xor(acc, off);
    if (lane == 0) q[wave] = acc + bq[wave];
}

// ---------------------------------------------------------------------------
// Kernel B: qW[h,c] = sum_d q[h*128+d] * Wk[(h*128+d), c]
// (bias qb/bk dropped: constant per head cancels in softmax over n)
// 32 blocks: block -> (h = blk>>3, ctile = (blk&7)*64). 256 threads:
// c = ctile + (t&63), dgroup = t>>6 sums 32 d's; LDS reduce across 4 groups.
// ---------------------------------------------------------------------------
__global__ void k_qw(const float* __restrict__ q, const float* __restrict__ Wk,
                     float* __restrict__ qW) {
    int h  = blockIdx.x >> 3;
    int c  = ((blockIdx.x & 7) << 6) + (threadIdx.x & 63);
    int dg = threadIdx.x >> 6;
    int hd0 = h * DD + dg * 32;
    float acc = 0.f;
#pragma unroll
    for (int i = 0; i < 32; ++i)
        acc += q[hd0 + i] * Wk[(size_t)(hd0 + i) * CC + c];
    __shared__ float red[4][64];
    red[dg][threadIdx.x & 63] = acc;
    __syncthreads();
    if (dg == 0)
        qW[h * CC + c] = red[0][c & 63] + red[1][c & 63] + red[2][c & 63] + red[3][c & 63];
}

// ---------------------------------------------------------------------------
// Kernel C: scores[h,n] = scale * dot(qW[h,:], x[0,0,n,:])
// 196 blocks x 64 threads (one wave per n); qW rows are L2-hot.
// ---------------------------------------------------------------------------
__global__ void k_scores(const float* __restrict__ x, const float* __restrict__ qW,
                         float* __restrict__ sc) {
    int n = blockIdx.x;
    int lane = threadIdx.x;
    const float scale = 0.08838834764831845f;                  // 1/sqrt(128)
    const float4* xr = (const float4*)(x + (size_t)n * CC);
    int c4a = lane * 2, c4b = c4a + 1;
    float4 xa = xr[c4a], xb = xr[c4b];
#pragma unroll
    for (int h = 0; h < HH; ++h) {
        const float4* qr = (const float4*)(qW + h * CC);
        float4 wa = qr[c4a], wb = qr[c4b];
        float acc = xa.x * wa.x + xa.y * wa.y + xa.z * wa.z + xa.w * wa.w +
                    xb.x * wb.x + xb.y * wb.y + xb.z * wb.z + xb.w * wb.w;
#pragma unroll
        for (int off = 32; off; off >>= 1) acc += __shfl_xor(acc, off);
        if (lane == 0) sc[h * NN + n] = scale * acc;
    }
}

// ---------------------------------------------------------------------------
// Kernel D: fused select + broadcast.
// Wave 0 of every block redundantly recomputes p from the 784 scores
// (3 KB, L2-broadcast): per-head softmax, mean over heads, top-10, p = max
// index among the 10 winners. Then all threads copy x[b,t,p,:] into both
// outputs (out0 = (B,T,10,C), out1 = identical reshape right after).
// ---------------------------------------------------------------------------
__global__ void __launch_bounds__(256) k_bcast_sel(
        const float* __restrict__ x, const float* __restrict__ sc,
        float* __restrict__ out) {
    __shared__ int sp;
    int tid = threadIdx.x;

    if (tid < 64) {
        int lane = tid;
        float pw0 = 0.f, pw1 = 0.f, pw2 = 0.f, pw3 = 0.f;
#pragma unroll
        for (int h = 0; h < HH; ++h) {
            float s0 = sc[h * NN + lane];
            float s1 = sc[h * NN + lane + 64];
            float s2 = sc[h * NN + lane + 128];
            float s3 = (lane + 192 < NN) ? sc[h * NN + lane + 192] : -1e30f;
            float m = fmaxf(fmaxf(s0, s1), fmaxf(s2, s3));
#pragma unroll
            for (int off = 32; off; off >>= 1) m = fmaxf(m, __shfl_xor(m, off));
            float e0 = expf(s0 - m), e1 = expf(s1 - m), e2 = expf(s2 - m);
            float e3 = (lane + 192 < NN) ? expf(s3 - m) : 0.f;
            float ss = e0 + e1 + e2 + e3;
#pragma unroll
            for (int off = 32; off; off >>= 1) ss += __shfl_xor(ss, off);
            float inv = 1.f / ss;
            pw0 += e0 * inv; pw1 += e1 * inv; pw2 += e2 * inv; pw3 += e3 * inv;
        }
        // top-10 over pw (values live in registers, 4 slots per lane)
        float v0 = pw0, v1 = pw1, v2 = pw2;
        float v3 = (lane + 192 < NN) ? pw3 : -2e30f;
        int p = -1;
        for (int r = 0; r < TOPM; ++r) {
            float v = -3e30f; int idx = -1;
            if (v0 >= v) { v = v0; idx = lane; }
            if (v1 >= v) { v = v1; idx = lane + 64; }
            if (v2 >= v) { v = v2; idx = lane + 128; }
            if (v3 >= v) { v = v3; idx = lane + 192; }
#pragma unroll
            for (int off = 32; off; off >>= 1) {
                float vo = __shfl_xor(v, off);
                int   io = __shfl_xor(idx, off);
                if (vo > v || (vo == v && io > idx)) { v = vo; idx = io; }
            }
            if ((idx & 63) == lane) {
                int jj = idx >> 6;
                if (jj == 0) v0 = -2e30f;
                else if (jj == 1) v1 = -2e30f;
                else if (jj == 2) v2 = -2e30f;
                else v3 = -2e30f;
            }
            if (idx > p) p = idx;
        }
        if (lane == 0) sp = p;
    }
    __syncthreads();
    int p = sp;

    int gt = blockIdx.x * 256 + tid;                // 0 .. BB*TT*128-1
    int bt = gt >> 7;
    int c4 = gt & 127;
    float4 v = ((const float4*)x)[((size_t)bt * NN + p) * 128 + c4];
    float4* o0 = (float4*)out + ((size_t)bt * TOPM) * 128 + c4;
    float4* o1 = o0 + (size_t)BB * TT * TOPM * 128;
#pragma unroll
    for (int m = 0; m < TOPM; ++m) {
        o0[(size_t)m * 128] = v;
        o1[(size_t)m * 128] = v;
    }
}

extern "C" void kernel_launch(void* const* d_in, const int* in_sizes, int n_in,
                              void* d_out, int out_size, void* d_ws, size_t ws_size,
                              hipStream_t stream) {
    const float* x   = (const float*)d_in[0];   // (16,60,196,512)
    const float* qst = (const float*)d_in[1];   // (16,512)
    const float* Wq  = (const float*)d_in[2];   // (512,512)
    const float* bq  = (const float*)d_in[3];   // (512,)
    const float* Wk  = (const float*)d_in[4];   // (512,512)
    // bk (d_in[5]) unused: per-head constant cancels in softmax over n

    float* ws  = (float*)d_ws;
    float* q   = ws;            // 512
    float* qW  = ws + 512;      // 2048
    float* sc  = ws + 2560;     // 784

    k_q        <<<128, 256, 0, stream>>>(qst, Wq, bq, q);
    k_qw       <<<32,  256, 0, stream>>>(q, Wk, qW);
    k_scores   <<<NN,   64, 0, stream>>>(x, qW, sc);
    k_bcast_sel<<<(BB * TT * 128) / 256, 256, 0, stream>>>(x, sc, (float*)d_out);
}